// Round 1
// baseline (209.161 us; speedup 1.0000x reference)
//
#include <hip/hip_runtime.h>
#include <hip/hip_bf16.h>

#define B 64
#define T 1024
#define C 768
#define TSPLIT 8            // t-chunks for partial reductions
#define TCHUNK (T / TSPLIT) // 128

// ---------------- ws layout (float offsets) ----------------
// [0]          : mode int (aliased)
// 64           : msum   [B][TSPLIT][C]
// +393216      : asum   [B][TSPLIT][C]
// +49152 each  : qsal, Q, qk
// scores       : [B][T]
// ppart        : [B][TSPLIT][C]
// pooled       : [B][C]
#define OFF_MSUM   64
#define OFF_ASUM   (OFF_MSUM + B*TSPLIT*C)
#define OFF_QSAL   (OFF_ASUM + B*TSPLIT*C)
#define OFF_Q      (OFF_QSAL + B*C)
#define OFF_QK     (OFF_Q + B*C)
#define OFF_SCORES (OFF_QK + B*C)
#define OFF_PPART  (OFF_SCORES + B*T)
#define OFF_POOLED (OFF_PPART + B*TSPLIT*C)

__device__ __forceinline__ bool read_mask(const void* mask, int mode, int idx) {
    if (mode == 1) return ((const unsigned char*)mask)[idx] != 0;
    if (mode == 2) return ((const float*)mask)[idx] != 0.0f;
    return ((const int*)mask)[idx] != 0;
}

// K0: detect mask dtype. Safe: reads only first 64KB (= bool-size of B*T mask).
__global__ void k_detect(const void* mask, int* mode_out) {
    __shared__ int s_not01, s_isf;
    int tid = threadIdx.x;
    if (tid == 0) { s_not01 = 0; s_isf = 0; }
    __syncthreads();
    const int* mi = (const int*)mask;
    int not01 = 0, isf = 0;
    for (int k = 0; k < 64; ++k) {
        int v = mi[tid + 256 * k];      // 256*64 = 16384 ints = 64KB
        if (v != 0 && v != 1) not01 = 1;
        if (v == 0x3F800000) isf = 1;
    }
    if (not01) atomicOr(&s_not01, 1);
    if (isf)   atomicOr(&s_isf, 1);
    __syncthreads();
    if (tid == 0) *mode_out = s_isf ? 2 : (s_not01 ? 1 : 0);
}

// K_A: per (b, t-chunk): partial masked-sum and all-sum over t for all C.
// 192 threads, each owns 4 consecutive c (float4).
__global__ void k_partial_sums(const float* __restrict__ tokens, const void* mask,
                               const int* modep, float* __restrict__ msum,
                               float* __restrict__ asum) {
    int ts = blockIdx.x, b = blockIdx.y, tid = threadIdx.x;
    int mode = *modep;
    int c = tid * 4;
    float4 ms = {0, 0, 0, 0}, as = {0, 0, 0, 0};
    const float* tb = tokens + (size_t)b * T * C;
    for (int t = ts * TCHUNK; t < ts * TCHUNK + TCHUNK; ++t) {
        float4 x = *(const float4*)(tb + (size_t)t * C + c);
        as.x += x.x; as.y += x.y; as.z += x.z; as.w += x.w;
        if (read_mask(mask, mode, b * T + t)) {
            ms.x += x.x; ms.y += x.y; ms.z += x.z; ms.w += x.w;
        }
    }
    size_t o = (size_t)(b * TSPLIT + ts) * C + c;
    *(float4*)(msum + o) = ms;
    *(float4*)(asum + o) = as;
}

// K_B: per b: cnt, then q_sal[b,c].
__global__ void k_qsal(const void* mask, const int* modep,
                       const float* __restrict__ msum, const float* __restrict__ asum,
                       float* __restrict__ qsal) {
    int b = blockIdx.x, tid = threadIdx.x;
    int mode = *modep;
    __shared__ float red[256];
    float cnt0 = 0.f;
    for (int t = tid; t < T; t += 256)
        cnt0 += read_mask(mask, mode, b * T + t) ? 1.f : 0.f;
    red[tid] = cnt0;
    __syncthreads();
    for (int s = 128; s > 0; s >>= 1) {
        if (tid < s) red[tid] += red[tid + s];
        __syncthreads();
    }
    float cnt = red[0];
    float scale = (cnt > 0.f) ? (1.f / fmaxf(cnt, 1.f)) : (1.f / (float)T);
    bool use_masked = (cnt > 0.f);
    for (int c = tid; c < C; c += 256) {
        float m = 0.f, a = 0.f;
        for (int p = 0; p < TSPLIT; ++p) {
            m += msum[(size_t)(b * TSPLIT + p) * C + c];
            a += asum[(size_t)(b * TSPLIT + p) * C + c];
        }
        qsal[b * C + c] = (use_masked ? m : a) * scale;
    }
}

// K_C: Q[b,d] = sum_c qsal[b,c] * Wq[d,c].  One thread per (b,d).
__global__ void k_rowdot(const float* __restrict__ vin, const float* __restrict__ W,
                         float* __restrict__ vout, float scale) {
    int gid = blockIdx.x * 256 + threadIdx.x;
    int b = gid / C, d = gid - b * C;
    const float4* v = (const float4*)(vin + (size_t)b * C);
    const float4* w = (const float4*)(W + (size_t)d * C);
    float acc = 0.f;
#pragma unroll 4
    for (int j = 0; j < C / 4; ++j) {
        float4 a = v[j], x = w[j];
        acc += a.x * x.x + a.y * x.y + a.z * x.z + a.w * x.w;
    }
    vout[gid] = acc * scale;
}

// K_D: qk[b,c] = (1/sqrt(C)) * sum_d Q[b,d] * Wk[d,c].  One thread per (b,c).
__global__ void k_coldot(const float* __restrict__ Q, const float* __restrict__ Wk,
                         float* __restrict__ qk) {
    int gid = blockIdx.x * 256 + threadIdx.x;
    int b = gid / C, c = gid - b * C;
    const float* Qb = Q + (size_t)b * C;
    float acc = 0.f;
#pragma unroll 8
    for (int d = 0; d < C; ++d)
        acc += Qb[d] * Wk[(size_t)d * C + c];
    qk[gid] = acc * 0.03608439182435161f; // 1/sqrt(768)
}

// K_E: scores[b,t] = tokens[b,t,:] . qk[b,:]  (qk pre-scaled).
// grid (TSPLIT, B), 256 threads = 4 waves; each wave does 32 t's.
__global__ void k_scores(const float* __restrict__ tokens, const float* __restrict__ qk,
                         float* __restrict__ scores) {
    __shared__ float sq[C];
    int ts = blockIdx.x, b = blockIdx.y, tid = threadIdx.x;
    for (int c = tid; c < C; c += 256) sq[c] = qk[b * C + c];
    __syncthreads();
    int wave = tid >> 6, lane = tid & 63;
    const float* tb = tokens + (size_t)b * T * C;
    for (int i = 0; i < TCHUNK / 4; ++i) {
        int t = ts * TCHUNK + wave * (TCHUNK / 4) + i;
        const float4* row = (const float4*)(tb + (size_t)t * C);
        const float4* q4 = (const float4*)sq;
        float acc = 0.f;
#pragma unroll
        for (int j = 0; j < 3; ++j) {
            int idx = lane + 64 * j;   // 192 float4 = 768 floats
            float4 x = row[idx], q = q4[idx];
            acc += x.x * q.x + x.y * q.y + x.z * q.z + x.w * q.w;
        }
        for (int s = 32; s > 0; s >>= 1) acc += __shfl_xor(acc, s);
        if (lane == 0) scores[b * T + t] = acc;
    }
}

// K_F: softmax over T per b; writes attn directly to d_out section 2.
__global__ void k_softmax(const float* __restrict__ scores, float* __restrict__ attn) {
    int b = blockIdx.x, tid = threadIdx.x;
    __shared__ float red[256];
    float4 s4 = ((const float4*)(scores + (size_t)b * T))[tid];
    float mx = fmaxf(fmaxf(s4.x, s4.y), fmaxf(s4.z, s4.w));
    red[tid] = mx;
    __syncthreads();
    for (int s = 128; s > 0; s >>= 1) {
        if (tid < s) red[tid] = fmaxf(red[tid], red[tid + s]);
        __syncthreads();
    }
    mx = red[0];
    __syncthreads();
    float4 e;
    e.x = expf(s4.x - mx); e.y = expf(s4.y - mx);
    e.z = expf(s4.z - mx); e.w = expf(s4.w - mx);
    red[tid] = e.x + e.y + e.z + e.w;
    __syncthreads();
    for (int s = 128; s > 0; s >>= 1) {
        if (tid < s) red[tid] += red[tid + s];
        __syncthreads();
    }
    float inv = 1.f / red[0];
    float4 o = {e.x * inv, e.y * inv, e.z * inv, e.w * inv};
    ((float4*)(attn + (size_t)b * T))[tid] = o;
}

// K_G: pooled partials: ppart[b,ts,c] = sum_{t in chunk} attn[b,t]*tokens[b,t,c].
__global__ void k_pool_partial(const float* __restrict__ tokens, const float* __restrict__ attn,
                               float* __restrict__ ppart) {
    int ts = blockIdx.x, b = blockIdx.y, tid = threadIdx.x;
    int c = tid * 4;
    float4 acc = {0, 0, 0, 0};
    const float* tb = tokens + (size_t)b * T * C;
    for (int t = ts * TCHUNK; t < ts * TCHUNK + TCHUNK; ++t) {
        float a = attn[(size_t)b * T + t];
        float4 x = *(const float4*)(tb + (size_t)t * C + c);
        acc.x += a * x.x; acc.y += a * x.y; acc.z += a * x.z; acc.w += a * x.w;
    }
    *(float4*)(ppart + (size_t)(b * TSPLIT + ts) * C + c) = acc;
}

// K_G2: pooled[b,c] = sum_ts ppart[b,ts,c].
__global__ void k_pool_reduce(const float* __restrict__ ppart, float* __restrict__ pooled) {
    int gid = blockIdx.x * 256 + threadIdx.x;
    int b = gid / C, c = gid - b * C;
    float a = 0.f;
#pragma unroll
    for (int p = 0; p < TSPLIT; ++p)
        a += ppart[(size_t)(b * TSPLIT + p) * C + c];
    pooled[gid] = a;
}

extern "C" void kernel_launch(void* const* d_in, const int* in_sizes, int n_in,
                              void* d_out, int out_size, void* d_ws, size_t ws_size,
                              hipStream_t stream) {
    const float* tokens = (const float*)d_in[0];
    const void*  mask   = d_in[1];
    const float* Wq     = (const float*)d_in[2];
    const float* Wk     = (const float*)d_in[3];
    const float* Wv     = (const float*)d_in[4];

    float* ws     = (float*)d_ws;
    int*   mode   = (int*)d_ws;
    float* msum   = ws + OFF_MSUM;
    float* asum   = ws + OFF_ASUM;
    float* qsal   = ws + OFF_QSAL;
    float* Qv     = ws + OFF_Q;
    float* qk     = ws + OFF_QK;
    float* scores = ws + OFF_SCORES;
    float* ppart  = ws + OFF_PPART;
    float* pooled = ws + OFF_POOLED;

    float* v_fg = (float*)d_out;            // [B][C]
    float* attn = (float*)d_out + B * C;    // [B][T]

    k_detect<<<1, 256, 0, stream>>>(mask, mode);
    k_partial_sums<<<dim3(TSPLIT, B), 192, 0, stream>>>(tokens, mask, mode, msum, asum);
    k_qsal<<<B, 256, 0, stream>>>(mask, mode, msum, asum, qsal);
    k_rowdot<<<(B * C) / 256, 256, 0, stream>>>(qsal, Wq, Qv, 1.0f);   // Q
    k_coldot<<<(B * C) / 256, 256, 0, stream>>>(Qv, Wk, qk);           // qk (pre-scaled)
    k_scores<<<dim3(TSPLIT, B), 256, 0, stream>>>(tokens, qk, scores);
    k_softmax<<<B, 256, 0, stream>>>(scores, attn);
    k_pool_partial<<<dim3(TSPLIT, B), 192, 0, stream>>>(tokens, attn, ppart);
    k_pool_reduce<<<(B * C) / 256, 256, 0, stream>>>(ppart, pooled);
    k_rowdot<<<(B * C) / 256, 256, 0, stream>>>(pooled, Wv, v_fg, 1.0f); // v_fg
}